// Round 6
// baseline (216.892 us; speedup 1.0000x reference)
//
#include <hip/hip_runtime.h>
#include <stdint.h>

#define IN_C  256
#define HID   256
#define OUT_C 128
#define SCAN_BS 1024

typedef __bf16 bf16x8 __attribute__((ext_vector_type(8)));
typedef float  f32x4  __attribute__((ext_vector_type(4)));
typedef unsigned short u16x8 __attribute__((ext_vector_type(8)));
typedef unsigned short u16x4 __attribute__((ext_vector_type(4)));
typedef unsigned short u16x2 __attribute__((ext_vector_type(2)));
typedef unsigned int u32;

static __device__ __forceinline__ unsigned short f2b(float f) {
    union { float f; uint32_t u; } v; v.f = f;
    uint32_t r = v.u + 0x7fffu + ((v.u >> 16) & 1u);
    return (unsigned short)(r >> 16);
}
static __device__ __forceinline__ float b2f(unsigned short b) {
    union { uint32_t u; float f; } v; v.u = ((uint32_t)b) << 16;
    return v.f;
}

// async global->LDS, 16B per lane (dest must be linear base + lane*16)
typedef __attribute__((address_space(1))) const u32 gas_u32;
typedef __attribute__((address_space(3))) u32 las_u32;
static __device__ __forceinline__ void gld16(const void* g, void* l) {
    __builtin_amdgcn_global_load_lds((gas_u32*)g, (las_u32*)l, 16, 0, 0);
}
// pack 2 f32 -> u32 of 2 bf16 (RNE), 1 VALU op
static __device__ __forceinline__ u32 cvtpk(float lo, float hi) {
    u32 r;
    asm("v_cvt_pk_bf16_f32 %0, %1, %2" : "=v"(r) : "v"(lo), "v"(hi));
    return r;
}

// ---------------- CSR build (self-loop folded in; per-edge weight precomputed) ----
__global__ void k_zero_i(int* __restrict__ p, int n) {
    int i = blockIdx.x * blockDim.x + threadIdx.x;
    if (i < n) p[i] = 0;
}

__global__ void k_count(const int* __restrict__ dst, int* __restrict__ cnt, int e) {
    int i = blockIdx.x * blockDim.x + threadIdx.x;
    if (i < e) atomicAdd(&cnt[dst[i]], 1);
}

__global__ __launch_bounds__(SCAN_BS) void k_scan_block(
    const int* __restrict__ cnt, int* __restrict__ rs, int* __restrict__ bsum, int n) {
    __shared__ int s[SCAN_BS];
    const int tid = threadIdx.x;
    const int i = blockIdx.x * SCAN_BS + tid;
    int v = (i < n) ? cnt[i] + 1 : 0;
    s[tid] = v;
    __syncthreads();
    for (int off = 1; off < SCAN_BS; off <<= 1) {
        int t = (tid >= off) ? s[tid - off] : 0;
        __syncthreads();
        s[tid] += t;
        __syncthreads();
    }
    if (i < n) rs[i] = s[tid] - v;
    if (tid == SCAN_BS - 1) bsum[blockIdx.x] = s[tid];
}

__global__ void k_scan_sums(int* __restrict__ bsum, int nb) {
    __shared__ int s[128];
    const int tid = threadIdx.x;
    int v = (tid < nb) ? bsum[tid] : 0;
    s[tid] = v;
    __syncthreads();
    for (int off = 1; off < 128; off <<= 1) {
        int t = (tid >= off) ? s[tid - off] : 0;
        __syncthreads();
        s[tid] += t;
        __syncthreads();
    }
    if (tid < nb) bsum[tid] = s[tid] - v;
}

__global__ void k_scan_add(int* __restrict__ rs, int* __restrict__ cur,
                           const int* __restrict__ bsum, const int* __restrict__ cnt,
                           float* __restrict__ dinv, int2* __restrict__ csrw, int n) {
    int i = blockIdx.x * blockDim.x + threadIdx.x;
    if (i < n) {
        int v = rs[i] + bsum[i >> 10];
        rs[i] = v;
        cur[i] = v + 1;
        float dp1 = (float)(cnt[i] + 1);
        dinv[i] = rsqrtf(dp1);
        csrw[v] = make_int2(i, __float_as_int(1.0f / dp1));   // self: weight = dinv^2
    }
}

__global__ void k_fill(const int* __restrict__ src, const int* __restrict__ dst,
                       const float* __restrict__ dinv,
                       int* __restrict__ cur, int2* __restrict__ csrw, int e) {
    int i = blockIdx.x * blockDim.x + threadIdx.x;
    if (i < e) {
        int s = src[i], d = dst[i];
        int p = atomicAdd(&cur[d], 1);
        csrw[p] = make_int2(s, __float_as_int(dinv[s] * dinv[d]));
    }
}

__global__ void k_prep(const float* __restrict__ W1, const float* __restrict__ W2,
                       unsigned short* __restrict__ W1T, unsigned short* __restrict__ W2T) {
    int i = blockIdx.x * blockDim.x + threadIdx.x;
    if (i < 65536) W1T[i] = f2b(W1[(i & 255) * HID + (i >> 8)]);
    if (i < 32768) W2T[i] = f2b(W2[(i & 255) * OUT_C + (i >> 8)]);
}

// ---------------- GEMM1: t1[n][256] bf16 = x(f32) @ W1 ----------------------
// BM=128, BN=128, BK=32; 256 thr = 4 waves (2x2), wave tile 64x64.
// A staged f32 via global_load_lds (inverse-swizzled source), converted at
// frag load with v_cvt_pk_bf16_f32. B staged bf16 linear (row stride 64B is
// naturally bank-uniform).
__global__ __launch_bounds__(256) void k_gemm1(
    const float* __restrict__ x, const unsigned short* __restrict__ W1T,
    unsigned short* __restrict__ t1, int n) {
    __shared__ __align__(16) float Af[128 * 32];           // 16 KiB
    __shared__ __align__(16) unsigned short Bs[128 * 32];  // 8 KiB
    const int tid = threadIdx.x;
    const int bm = blockIdx.x >> 1, bn = blockIdx.x & 1;
    const int row0 = bm * 128, col0 = bn * 128;
    const int wid = tid >> 6, lane = tid & 63;
    const int wm = wid >> 1, wn = wid & 1;
    const int lrow = lane & 15, lgrp = lane >> 4;

    f32x4 acc[4][4];
    #pragma unroll
    for (int i = 0; i < 4; ++i)
        #pragma unroll
        for (int j = 0; j < 4; ++j)
            acc[i][j] = (f32x4){0.f, 0.f, 0.f, 0.f};

    for (int kt = 0; kt < 8; ++kt) {
        // A: 1024 granules of 16B (4 f32); LDS linear, global source pre-swizzled
        #pragma unroll
        for (int i = 0; i < 4; ++i) {
            int s = tid + 256 * i;
            int r = s >> 3, c = s & 7;
            int grow = row0 + r; if (grow > n - 1) grow = n - 1;
            gld16(x + (size_t)grow * IN_C + kt * 32 + ((c ^ (r & 7)) << 2), Af + s * 4);
        }
        // B: 512 granules of 16B (8 bf16), linear
        #pragma unroll
        for (int i = 0; i < 2; ++i) {
            int s = tid + 256 * i;
            int nn = s >> 2, c = s & 3;
            gld16(W1T + (size_t)(col0 + nn) * 256 + kt * 32 + c * 8, Bs + s * 8);
        }
        __syncthreads();   // drains vmcnt (gld_lds) + lgkmcnt

        bf16x8 av[4], bv[4];
        #pragma unroll
        for (int mf = 0; mf < 4; ++mf) {
            int r = wm * 64 + mf * 16 + lrow;
            f32x4 l = *(const f32x4*)&Af[r * 32 + (((2 * lgrp) ^ (r & 7)) << 2)];
            f32x4 h = *(const f32x4*)&Af[r * 32 + (((2 * lgrp + 1) ^ (r & 7)) << 2)];
            union { u32 w[4]; bf16x8 b; } u;
            u.w[0] = cvtpk(l[0], l[1]); u.w[1] = cvtpk(l[2], l[3]);
            u.w[2] = cvtpk(h[0], h[1]); u.w[3] = cvtpk(h[2], h[3]);
            av[mf] = u.b;
        }
        #pragma unroll
        for (int nf = 0; nf < 4; ++nf) {
            int cc = wn * 64 + nf * 16 + lrow;
            bv[nf] = *(const bf16x8*)&Bs[cc * 32 + lgrp * 8];
        }
        #pragma unroll
        for (int mf = 0; mf < 4; ++mf)
            #pragma unroll
            for (int nf = 0; nf < 4; ++nf)
                acc[mf][nf] = __builtin_amdgcn_mfma_f32_16x16x32_bf16(
                    av[mf], bv[nf], acc[mf][nf], 0, 0, 0);
        __syncthreads();
    }
    #pragma unroll
    for (int mf = 0; mf < 4; ++mf)
        #pragma unroll
        for (int j = 0; j < 4; ++j) {
            int grow = row0 + wm * 64 + mf * 16 + lgrp * 4 + j;
            if (grow < n) {
                #pragma unroll
                for (int nf = 0; nf < 4; ++nf) {
                    int col = col0 + wn * 64 + nf * 16 + lrow;
                    t1[(size_t)grow * HID + col] = f2b(acc[mf][nf][j]);
                }
            }
        }
}

// ---------------- agg1: out1 = relu(gather(t1) + b1) ------------------------
__global__ __launch_bounds__(256) void k_agg1(
    const unsigned short* __restrict__ t1, const int* __restrict__ rs,
    const int* __restrict__ cnt, const int2* __restrict__ csrw,
    const float* __restrict__ b1, unsigned short* __restrict__ out1, int n) {
    const int w = blockIdx.x * 4 + (threadIdx.x >> 6);
    const int nodeA = w * 2, nodeB = w * 2 + 1;
    if (nodeA >= n) return;
    const bool hasB = (nodeB < n);
    const int lane = threadIdx.x & 63;
    const int ch = lane * 4;
    const int begA = rs[nodeA], mA = cnt[nodeA] + 1;
    int begB = 0, mB = 0;
    if (hasB) { begB = rs[nodeB]; mB = cnt[nodeB] + 1; }
    float a0 = 0.f, a1 = 0.f, a2 = 0.f, a3 = 0.f;
    float c0 = 0.f, c1 = 0.f, c2 = 0.f, c3 = 0.f;
    const int mmax = mA > mB ? mA : mB;
    for (int j = 0; j < mmax; ++j) {
        if (j < mA) {
            int2 p = csrw[begA + j];
            float wA = __int_as_float(p.y);
            u16x4 u = *(const u16x4*)&t1[(size_t)p.x * HID + ch];
            a0 += b2f(u[0]) * wA; a1 += b2f(u[1]) * wA;
            a2 += b2f(u[2]) * wA; a3 += b2f(u[3]) * wA;
        }
        if (j < mB) {
            int2 p = csrw[begB + j];
            float wB = __int_as_float(p.y);
            u16x4 u = *(const u16x4*)&t1[(size_t)p.x * HID + ch];
            c0 += b2f(u[0]) * wB; c1 += b2f(u[1]) * wB;
            c2 += b2f(u[2]) * wB; c3 += b2f(u[3]) * wB;
        }
    }
    float4 bb = *(const float4*)(b1 + ch);
    u16x4 o;
    o[0] = f2b(fmaxf(a0 + bb.x, 0.f));
    o[1] = f2b(fmaxf(a1 + bb.y, 0.f));
    o[2] = f2b(fmaxf(a2 + bb.z, 0.f));
    o[3] = f2b(fmaxf(a3 + bb.w, 0.f));
    *(u16x4*)&out1[(size_t)nodeA * HID + ch] = o;
    if (hasB) {
        u16x4 q;
        q[0] = f2b(fmaxf(c0 + bb.x, 0.f));
        q[1] = f2b(fmaxf(c1 + bb.y, 0.f));
        q[2] = f2b(fmaxf(c2 + bb.z, 0.f));
        q[3] = f2b(fmaxf(c3 + bb.w, 0.f));
        *(u16x4*)&out1[(size_t)nodeB * HID + ch] = q;
    }
}

// ---------------- GEMM2: t2[n][128] bf16 = out1(bf16) @ W2 ------------------
// BM=128, BN=128 (full), BK=32; 256 thr = 4 waves (2x2). All-bf16: gld_lds
// direct for A and B, linear layouts (64B row stride is bank-uniform).
__global__ __launch_bounds__(256) void k_gemm2(
    const unsigned short* __restrict__ out1, const unsigned short* __restrict__ W2T,
    unsigned short* __restrict__ t2, int n) {
    __shared__ __align__(16) unsigned short Ah[128 * 32];   // 8 KiB
    __shared__ __align__(16) unsigned short Bs[128 * 32];   // 8 KiB
    const int tid = threadIdx.x;
    const int row0 = blockIdx.x * 128;
    const int wid = tid >> 6, lane = tid & 63;
    const int wm = wid >> 1, wn = wid & 1;
    const int lrow = lane & 15, lgrp = lane >> 4;

    f32x4 acc[4][4];
    #pragma unroll
    for (int i = 0; i < 4; ++i)
        #pragma unroll
        for (int j = 0; j < 4; ++j)
            acc[i][j] = (f32x4){0.f, 0.f, 0.f, 0.f};

    for (int kt = 0; kt < 8; ++kt) {
        #pragma unroll
        for (int i = 0; i < 2; ++i) {
            int s = tid + 256 * i;
            int r = s >> 2, c = s & 3;
            int grow = row0 + r; if (grow > n - 1) grow = n - 1;
            gld16(out1 + (size_t)grow * HID + kt * 32 + c * 8, Ah + s * 8);
        }
        #pragma unroll
        for (int i = 0; i < 2; ++i) {
            int s = tid + 256 * i;
            int nn = s >> 2, c = s & 3;
            gld16(W2T + (size_t)nn * 256 + kt * 32 + c * 8, Bs + s * 8);
        }
        __syncthreads();

        bf16x8 av[4], bv[4];
        #pragma unroll
        for (int mf = 0; mf < 4; ++mf) {
            int r = wm * 64 + mf * 16 + lrow;
            av[mf] = *(const bf16x8*)&Ah[r * 32 + lgrp * 8];
        }
        #pragma unroll
        for (int nf = 0; nf < 4; ++nf) {
            int cc = wn * 64 + nf * 16 + lrow;
            bv[nf] = *(const bf16x8*)&Bs[cc * 32 + lgrp * 8];
        }
        #pragma unroll
        for (int mf = 0; mf < 4; ++mf)
            #pragma unroll
            for (int nf = 0; nf < 4; ++nf)
                acc[mf][nf] = __builtin_amdgcn_mfma_f32_16x16x32_bf16(
                    av[mf], bv[nf], acc[mf][nf], 0, 0, 0);
        __syncthreads();
    }
    #pragma unroll
    for (int mf = 0; mf < 4; ++mf)
        #pragma unroll
        for (int j = 0; j < 4; ++j) {
            int grow = row0 + wm * 64 + mf * 16 + lgrp * 4 + j;
            if (grow < n) {
                #pragma unroll
                for (int nf = 0; nf < 4; ++nf) {
                    int col = wn * 64 + nf * 16 + lrow;
                    t2[(size_t)grow * OUT_C + col] = f2b(acc[mf][nf][j]);
                }
            }
        }
}

// ---------------- agg2: out(f32) = gather(t2) + b2 --------------------------
__global__ __launch_bounds__(256) void k_agg2(
    const unsigned short* __restrict__ t2, const int* __restrict__ rs,
    const int* __restrict__ cnt, const int2* __restrict__ csrw,
    const float* __restrict__ b2, float* __restrict__ out, int n) {
    const int w = blockIdx.x * 4 + (threadIdx.x >> 6);
    const int nodeA = w * 2, nodeB = w * 2 + 1;
    if (nodeA >= n) return;
    const bool hasB = (nodeB < n);
    const int lane = threadIdx.x & 63;
    const int ch = lane * 2;
    const int begA = rs[nodeA], mA = cnt[nodeA] + 1;
    int begB = 0, mB = 0;
    if (hasB) { begB = rs[nodeB]; mB = cnt[nodeB] + 1; }
    float a0 = 0.f, a1 = 0.f, c0 = 0.f, c1 = 0.f;
    const int mmax = mA > mB ? mA : mB;
    for (int j = 0; j < mmax; ++j) {
        if (j < mA) {
            int2 p = csrw[begA + j];
            float wA = __int_as_float(p.y);
            u16x2 u = *(const u16x2*)&t2[(size_t)p.x * OUT_C + ch];
            a0 += b2f(u[0]) * wA; a1 += b2f(u[1]) * wA;
        }
        if (j < mB) {
            int2 p = csrw[begB + j];
            float wB = __int_as_float(p.y);
            u16x2 u = *(const u16x2*)&t2[(size_t)p.x * OUT_C + ch];
            c0 += b2f(u[0]) * wB; c1 += b2f(u[1]) * wB;
        }
    }
    float2 bb = *(const float2*)(b2 + ch);
    *(float2*)&out[(size_t)nodeA * OUT_C + ch] = make_float2(a0 + bb.x, a1 + bb.y);
    if (hasB)
        *(float2*)&out[(size_t)nodeB * OUT_C + ch] = make_float2(c0 + bb.x, c1 + bb.y);
}

extern "C" void kernel_launch(void* const* d_in, const int* in_sizes, int n_in,
                              void* d_out, int out_size, void* d_ws, size_t ws_size,
                              hipStream_t stream) {
    const float* x  = (const float*)d_in[0];
    const int*   ei = (const int*)d_in[1];
    const float* W1 = (const float*)d_in[2];
    const float* b1 = (const float*)d_in[3];
    const float* W2 = (const float*)d_in[4];
    const float* b2 = (const float*)d_in[5];
    float* out = (float*)d_out;

    const int n = in_sizes[0] / IN_C;   // 100000
    const int e = in_sizes[1] / 2;      // 300000
    const int* src = ei;
    const int* dst = ei + e;

    // workspace layout (4B words; csrw 8B-aligned, t1 16B-aligned)
    int*   cnt  = (int*)d_ws;                       // [n]
    int*   rs   = cnt + n;                          // [n]
    int*   cur  = rs + n;                           // [n]
    int*   bsum = cur + n;                          // [128]
    float* dinv = (float*)(bsum + 128);             // [n]
    int2*  csrw = (int2*)(dinv + n);                // [e+n] pairs {src, weight}
    unsigned short* W1T = (unsigned short*)(csrw + (size_t)e + n);  // [256*256]
    unsigned short* W2T = W1T + 65536;                              // [128*256]
    unsigned short* t1  = W2T + 32768;                              // [n*HID]
    unsigned short* out1 = t1 + (size_t)n * HID;                    // [n*HID]
    unsigned short* t2  = t1;                                       // alias

    const int nb = (n + SCAN_BS - 1) / SCAN_BS;

    k_zero_i<<<(n + 255) / 256, 256, 0, stream>>>(cnt, n);
    k_count<<<(e + 255) / 256, 256, 0, stream>>>(dst, cnt, e);
    k_scan_block<<<nb, SCAN_BS, 0, stream>>>(cnt, rs, bsum, n);
    k_scan_sums<<<1, 128, 0, stream>>>(bsum, nb);
    k_scan_add<<<(n + 255) / 256, 256, 0, stream>>>(rs, cur, bsum, cnt, dinv, csrw, n);
    k_fill<<<(e + 255) / 256, 256, 0, stream>>>(src, dst, dinv, cur, csrw, e);
    k_prep<<<256, 256, 0, stream>>>(W1, W2, W1T, W2T);

    const int mb = (n + 127) / 128;       // 782
    k_gemm1<<<mb * 2, 256, 0, stream>>>(x, W1T, t1, n);
    const int aggblk = (n + 7) / 8;
    k_agg1<<<aggblk, 256, 0, stream>>>(t1, rs, cnt, csrw, b1, out1, n);
    k_gemm2<<<mb, 256, 0, stream>>>(out1, W2T, t2, n);
    k_agg2<<<aggblk, 256, 0, stream>>>(t2, rs, cnt, csrw, b2, out, n);
}